// Round 2
// baseline (166.848 us; speedup 1.0000x reference)
//
#include <hip/hip_runtime.h>

#define NPTS   65536
#define TOTAL  (2 * NPTS)
#define NUNITS 1024            // units of 128 points

typedef __attribute__((ext_vector_type(8)))  short short8;
typedef __attribute__((ext_vector_type(16))) float float16;
union F8 { uint4 u; short8 s; };

// ws byte offsets
#define WS_STRIPE 0                               // fp32[16][128], memset 0
#define WS_T1A    8192                            // bf16[TOTAL][32] f_nei, 64B rows
#define WS_T1B    (8192 + TOTAL * 64)             // (unused now; kept for layout stability)
#define WS_T2     (8192 + TOTAL * 64 + TOTAL * 8) // bf16[TOTAL][32] feat, 64B rows

__device__ __forceinline__ unsigned short f2bf(float x) {
    unsigned u = __float_as_uint(x);
    return (unsigned short)((u + 0x7FFFu + ((u >> 16) & 1u)) >> 16);
}
__device__ __forceinline__ unsigned pk2(float a, float b) {
    return (unsigned)f2bf(a) | ((unsigned)f2bf(b) << 16);
}
__device__ __forceinline__ float relu(float x) { return x > 0.f ? x : 0.f; }
__device__ __forceinline__ uint4 pk8(const float* e) {
    uint4 u;
    u.x = pk2(e[0], e[1]); u.y = pk2(e[2], e[3]);
    u.z = pk2(e[4], e[5]); u.w = pk2(e[6], e[7]);
    return u;
}
__device__ __forceinline__ float16 zero16() {
    float16 z;
#pragma unroll
    for (int i = 0; i < 16; i++) z[i] = 0.f;
    return z;
}

// ===== K0: tnet trunk + block max + striped atomics; f_nei GEMM + feat copy =====
__global__ __launch_bounds__(256) void kP0(
    const float* __restrict__ feature, const float* __restrict__ xyz,
    const float* __restrict__ tW1, const float* __restrict__ ts1, const float* __restrict__ tb1,
    const float* __restrict__ tW2, const float* __restrict__ ts2, const float* __restrict__ tb2,
    const float* __restrict__ W2,  const float* __restrict__ s2,  const float* __restrict__ b2,
    char* ws)
{
    __shared__ float red[4][64];
    float* stripe       = (float*)(ws + WS_STRIPE);
    unsigned short* t1a = (unsigned short*)(ws + WS_T1A);
    unsigned short* t2  = (unsigned short*)(ws + WS_T2);
    const int lane = threadIdx.x & 63, wv = threadIdx.x >> 6;
    const int col = lane & 31, h = lane >> 5;
    const float16 z = zero16();
    const int u = blockIdx.x;                   // 1024 blocks, 128 pts each
    const int b = u >> 9;
    float e[8];
    // trunk weights: tW1*ts1 (VALU side), tW2^T*ts2 (B-frags)
    float aw0[8], aw1[8], aw2[8], bb[8];
#pragma unroll
    for (int j = 0; j < 8; j++) {
        int k = 8 * h + j; float s = ts1[k];
        aw0[j] = tW1[k] * s; aw1[j] = tW1[16 + k] * s; aw2[j] = tW1[32 + k] * s;
        bb[j] = tb1[k];
    }
    F8 bf0, bf1;
#pragma unroll
    for (int j = 0; j < 8; j++) e[j] = tW2[(8 * h + j) * 64 + col] * ts2[col];
    bf0.u = pk8(e);
#pragma unroll
    for (int j = 0; j < 8; j++) e[j] = tW2[(8 * h + j) * 64 + 32 + col] * ts2[32 + col];
    bf1.u = pk8(e);
    // f_nei weights: W2^T folded as A-frags
    F8 a0, a1;
    float sc2 = s2[col];
#pragma unroll
    for (int j = 0; j < 8; j++) e[j] = W2[(8 * h + j) * 32 + col] * sc2;
    a0.u = pk8(e);
#pragma unroll
    for (int j = 0; j < 8; j++) e[j] = W2[(16 + 8 * h + j) * 32 + col] * sc2;
    a1.u = pk8(e);
    float b2v[16];
#pragma unroll
    for (int r = 0; r < 16; r++) b2v[r] = b2[(r & 3) + 8 * (r >> 2) + 4 * h];

    int base = u * 128 + wv * 32;
    // trunk + max
    const float* xp = xyz + (size_t)(base + col) * 3;
    float x0 = xp[0], x1 = xp[1], x2 = xp[2];
    float hv[8];
#pragma unroll
    for (int j = 0; j < 8; j++)
        hv[j] = relu(x0 * aw0[j] + x1 * aw1[j] + x2 * aw2[j] + bb[j]);
    F8 af; af.u = pk8(hv);
    float16 c0 = __builtin_amdgcn_mfma_f32_32x32x16_bf16(af.s, bf0.s, z, 0, 0, 0);
    float16 c1 = __builtin_amdgcn_mfma_f32_32x32x16_bf16(af.s, bf1.s, z, 0, 0, 0);
    float v0 = c0[0], v1 = c1[0];
#pragma unroll
    for (int i = 1; i < 16; i++) { v0 = fmaxf(v0, c0[i]); v1 = fmaxf(v1, c1[i]); }
    v0 = fmaxf(v0, __shfl_xor(v0, 32));
    v1 = fmaxf(v1, __shfl_xor(v1, 32));
    if (h == 0) { red[wv][col] = v0; red[wv][32 + col] = v1; }
    __syncthreads();
    if (threadIdx.x < 64) {
        int c = threadIdx.x;
        float m = fmaxf(fmaxf(red[0][c], red[1][c]), fmaxf(red[2][c], red[3][c]));
        float val = relu(m + tb2[c]);           // bias/relu after max: monotone, valid
        atomicMax((unsigned*)(stripe + (u & 15) * 128 + b * 64 + c), __float_as_uint(val));
    }
    // f_nei GEMM + raw feat copy
    int pt = base + col;
    const float* fb = feature + (size_t)b * 32 * NPTS + (pt & (NPTS - 1));
    float v[8];
    F8 f0, f1;
#pragma unroll
    for (int j = 0; j < 8; j++) v[j] = fb[(size_t)(8 * h + j) * NPTS];
    f0.u = pk8(v);
#pragma unroll
    for (int j = 0; j < 8; j++) v[j] = fb[(size_t)(16 + 8 * h + j) * NPTS];
    f1.u = pk8(v);
    *(uint4*)(t2 + (size_t)pt * 32 + 8 * h) = f0.u;
    *(uint4*)(t2 + (size_t)pt * 32 + 16 + 8 * h) = f1.u;
    float16 acc = z;
    acc = __builtin_amdgcn_mfma_f32_32x32x16_bf16(a0.s, f0.s, acc, 0, 0, 0);
    acc = __builtin_amdgcn_mfma_f32_32x32x16_bf16(a1.s, f1.s, acc, 0, 0, 0);
#pragma unroll
    for (int q = 0; q < 4; q++) {
        int r = 4 * q;
        uint2 uu;
        uu.x = pk2(relu(acc[r] + b2v[r]), relu(acc[r + 1] + b2v[r + 1]));
        uu.y = pk2(relu(acc[r + 2] + b2v[r + 2]), relu(acc[r + 3] + b2v[r + 3]));
        *(uint2*)(t1a + (size_t)pt * 32 + 8 * q + 4 * h) = uu;
    }
}

// ===== K23: tnet head folded into prologue + gather GEMM (f_xyz on the fly,
//       4-deep register prefetch) + max-over-K (LDS, same-wave) + output GEMM =====
__global__ __launch_bounds__(256) void kP23(
    const int* __restrict__ nidx, const float* __restrict__ xyz,
    const float* __restrict__ tW3, const float* __restrict__ ts3, const float* __restrict__ tb3,
    const float* __restrict__ tW4, const float* __restrict__ tb4,
    const float* __restrict__ W1,  const float* __restrict__ s1,  const float* __restrict__ b1,
    const float* __restrict__ W3,  const float* __restrict__ s3,  const float* __restrict__ b3,
    const float* __restrict__ W4,  const float* __restrict__ s4,  const float* __restrict__ b4,
    char* ws, float* __restrict__ out)
{
    __shared__ unsigned short mld[128 * 36];
    const float* stripe = (const float*)(ws + WS_STRIPE);
    const unsigned short* t1a = (const unsigned short*)(ws + WS_T1A);
    const unsigned short* t2  = (const unsigned short*)(ws + WS_T2);
    const int lane = threadIdx.x & 63, wv = threadIdx.x >> 6;
    const int col = lane & 31, h = lane >> 5;
    const float16 z = zero16();

    // XCD-batch affinity: blk&7 is XCD slot; slot>=4 -> batch 1
    int slot = blockIdx.x & 7, batch = slot >> 2;
    int grp = (blockIdx.x >> 3) * 4 + (slot & 3);   // [0, 512) within batch
    int u = batch * 512 + grp;
    int base = u * 128;

    // ---- tnet head prologue (identical op order to the old kP1) ----
    float hm = 0.f;                             // stripes >= 0; 0-init safe under max
#pragma unroll
    for (int s = 0; s < 16; s++)
        hm = fmaxf(hm, stripe[s * 128 + batch * 64 + lane]);
    float vv[16];                               // lane i contributes hm_i * tW3[i][:]
    {
        const float4* trow = (const float4*)(tW3 + lane * 16);
#pragma unroll
        for (int q = 0; q < 4; q++) {
            float4 t4 = trow[q];
            vv[4 * q + 0] = hm * t4.x; vv[4 * q + 1] = hm * t4.y;
            vv[4 * q + 2] = hm * t4.z; vv[4 * q + 3] = hm * t4.w;
        }
    }
#pragma unroll
    for (int off = 1; off < 64; off <<= 1) {
#pragma unroll
        for (int c = 0; c < 16; c++) vv[c] += __shfl_xor(vv[c], off);
    }
    float T[9];
#pragma unroll
    for (int j = 0; j < 9; j++) T[j] = tb4[j];
#pragma unroll
    for (int c = 0; c < 16; c++) {
        float h3 = relu(vv[c] * ts3[c] + tb3[c]);
#pragma unroll
        for (int j = 0; j < 9; j++) T[j] += h3 * tW4[c * 9 + j];
    }
    T[0] += 1.f; T[4] += 1.f; T[8] += 1.f;
    // all lanes convergent & identical after butterfly -> hoist to SGPRs
#pragma unroll
    for (int j = 0; j < 9; j++)
        T[j] = __uint_as_float(__builtin_amdgcn_readfirstlane(__float_as_uint(T[j])));

    float e[8];
    // W3^T folded B-frags (k>=35 zero)
    F8 w0, w1, w2, zf;
    zf.u.x = zf.u.y = zf.u.z = zf.u.w = 0u;
    float sc3 = s3[col];
#pragma unroll
    for (int j = 0; j < 8; j++) e[j] = W3[(8 * h + j) * 32 + col] * sc3;
    w0.u = pk8(e);
#pragma unroll
    for (int j = 0; j < 8; j++) e[j] = W3[(16 + 8 * h + j) * 32 + col] * sc3;
    w1.u = pk8(e);
    w2 = zf;
    if (h == 0) {
        float e2[8] = {0.f, 0.f, 0.f, 0.f, 0.f, 0.f, 0.f, 0.f};
#pragma unroll
        for (int j = 0; j < 3; j++) e2[j] = W3[(32 + j) * 32 + col] * sc3;
        w2.u = pk8(e2);
    }
    float b3v = b3[col];
    // W4^T folded A-frags
    F8 aw[4];
    float sc4 = s4[col];
#pragma unroll
    for (int t = 0; t < 4; t++) {
#pragma unroll
        for (int j = 0; j < 8; j++) e[j] = W4[(16 * t + 8 * h + j) * 32 + col] * sc4;
        aw[t].u = pk8(e);
    }
    float b4v[16];
#pragma unroll
    for (int r = 0; r < 16; r++) b4v[r] = b4[(r & 3) + 8 * (r >> 2) + 4 * h];

    // preload all 16 neighbor indices, packed 2 x u16 per VGPR (idx < 65536)
    unsigned idxp[8];
#pragma unroll
    for (int i2 = 0; i2 < 8; i2++) {
        unsigned lo = (unsigned)nidx[(base + 2 * (wv * 16 + 2 * i2)) * 16 + col];
        unsigned hi = (unsigned)nidx[(base + 2 * (wv * 16 + 2 * i2 + 1)) * 16 + col];
        idxp[i2] = (lo & 0xffffu) | (hi << 16);
    }

    // ---- gather loop: 4-deep explicit register prefetch ----
    // Each slot holds one iteration's gathered f_nei row halves (2x uint4) and
    // raw neighbor xyz (h==0 lanes). Statically unrolled -> all slot indices
    // compile-time (no scratch). f_xyz computed on the fly with the exact same
    // f32 op order + bf16 rounding the old kP1 used.
#define PF_DEPTH 4
    F8 pa0[PF_DEPTH], pa1[PF_DEPTH];
    float px0[PF_DEPTH], px1[PF_DEPTH], px2[PF_DEPTH];
#pragma unroll
    for (int it = 0; it < PF_DEPTH; it++) {
        unsigned row = (idxp[it >> 1] >> (16 * (it & 1))) & 0xffffu;
        size_t g = ((size_t)batch << 16) + row;
        const unsigned short* ap = t1a + g * 32;
        pa0[it].u = *(const uint4*)(ap + 8 * h);
        pa1[it].u = *(const uint4*)(ap + 16 + 8 * h);
        px0[it] = 0.f; px1[it] = 0.f; px2[it] = 0.f;
        if (h == 0) {
            const float* xp = xyz + g * 3;
            px0[it] = xp[0]; px1[it] = xp[1]; px2[it] = xp[2];
        }
    }
#pragma unroll
    for (int it = 0; it < 16; it++) {
        const int s = it & (PF_DEPTH - 1);
        F8 ca0 = pa0[s], ca1 = pa1[s];
        float cx0 = px0[s], cx1 = px1[s], cx2 = px2[s];
        if (it + PF_DEPTH < 16) {
            unsigned row = (idxp[(it + PF_DEPTH) >> 1] >> (16 * ((it + PF_DEPTH) & 1))) & 0xffffu;
            size_t g = ((size_t)batch << 16) + row;
            const unsigned short* ap = t1a + g * 32;
            pa0[s].u = *(const uint4*)(ap + 8 * h);
            pa1[s].u = *(const uint4*)(ap + 16 + 8 * h);
            if (h == 0) {
                const float* xp = xyz + g * 3;
                px0[s] = xp[0]; px1[s] = xp[1]; px2[s] = xp[2];
            }
        }
        F8 ca2 = zf;
        if (h == 0) {
            float q0 = cx0 * T[0] + cx1 * T[3] + cx2 * T[6];
            float q1 = cx0 * T[1] + cx1 * T[4] + cx2 * T[7];
            float q2 = cx0 * T[2] + cx1 * T[5] + cx2 * T[8];
            float r0 = relu((q0 * W1[0] + q1 * W1[3] + q2 * W1[6]) * s1[0] + b1[0]);
            float r1 = relu((q0 * W1[1] + q1 * W1[4] + q2 * W1[7]) * s1[1] + b1[1]);
            float r2 = relu((q0 * W1[2] + q1 * W1[5] + q2 * W1[8]) * s1[2] + b1[2]);
            ca2.u.x = pk2(r0, r1); ca2.u.y = pk2(r2, 0.f);
        }
        float16 acc = z;
        acc = __builtin_amdgcn_mfma_f32_32x32x16_bf16(ca0.s, w0.s, acc, 0, 0, 0);
        acc = __builtin_amdgcn_mfma_f32_32x32x16_bf16(ca1.s, w1.s, acc, 0, 0, 0);
        acc = __builtin_amdgcn_mfma_f32_32x32x16_bf16(ca2.s, w2.s, acc, 0, 0, 0);
        float vA = acc[0], vB = acc[8];
#pragma unroll
        for (int r = 1; r < 8; r++) { vA = fmaxf(vA, acc[r]); vB = fmaxf(vB, acc[8 + r]); }
        vA = fmaxf(vA, __shfl_xor(vA, 32));
        vB = fmaxf(vB, __shfl_xor(vB, 32));
        vA = relu(vA + b3v);
        vB = relu(vB + b3v);
        float val = h ? vB : vA;
        int pi = wv * 16 + it;
        mld[(2 * pi + h) * 36 + col] = f2bf(val);    // same-wave produce/consume
    }

    // output GEMM: 32 pts per wave; m read from LDS (same wave -> no barrier)
    int p_loc = wv * 32 + col;
    int p = base + p_loc;
    const unsigned short* bp = t2 + (size_t)p * 32 + 8 * h;
    F8 x0, x1, x2, x3;
    x0.u = *(const uint4*)(bp);
    x1.u = *(const uint4*)(bp + 16);
    const unsigned short* mp = mld + p_loc * 36;
    uint2 q0 = *(const uint2*)(mp + 8 * h);
    uint2 q1 = *(const uint2*)(mp + 8 * h + 4);
    uint2 q2 = *(const uint2*)(mp + 16 + 8 * h);
    uint2 q3 = *(const uint2*)(mp + 16 + 8 * h + 4);
    x2.u.x = q0.x; x2.u.y = q0.y; x2.u.z = q1.x; x2.u.w = q1.y;
    x3.u.x = q2.x; x3.u.y = q2.y; x3.u.z = q3.x; x3.u.w = q3.y;
    float16 acc = z;
    acc = __builtin_amdgcn_mfma_f32_32x32x16_bf16(aw[0].s, x0.s, acc, 0, 0, 0);
    acc = __builtin_amdgcn_mfma_f32_32x32x16_bf16(aw[1].s, x1.s, acc, 0, 0, 0);
    acc = __builtin_amdgcn_mfma_f32_32x32x16_bf16(aw[2].s, x2.s, acc, 0, 0, 0);
    acc = __builtin_amdgcn_mfma_f32_32x32x16_bf16(aw[3].s, x3.s, acc, 0, 0, 0);
    float* ob = out + (size_t)(batch * 32) * NPTS + (p & (NPTS - 1));
#pragma unroll
    for (int r = 0; r < 16; r++) {
        int o = (r & 3) + 8 * (r >> 2) + 4 * h;
        ob[(size_t)o * NPTS] = relu(acc[r] + b4v[r]);
    }
}

extern "C" void kernel_launch(void* const* d_in, const int* in_sizes, int n_in,
                              void* d_out, int out_size, void* d_ws, size_t ws_size,
                              hipStream_t stream)
{
    const float* feature = (const float*)d_in[0];
    const float* xyz     = (const float*)d_in[1];
    const int*   nidx    = (const int*)d_in[2];
    const float* tW1 = (const float*)d_in[3];
    const float* ts1 = (const float*)d_in[4];
    const float* tb1 = (const float*)d_in[5];
    const float* tW2 = (const float*)d_in[6];
    const float* ts2 = (const float*)d_in[7];
    const float* tb2 = (const float*)d_in[8];
    const float* tW3 = (const float*)d_in[9];
    const float* ts3 = (const float*)d_in[10];
    const float* tb3 = (const float*)d_in[11];
    const float* tW4 = (const float*)d_in[12];
    const float* tb4 = (const float*)d_in[13];
    const float* W1  = (const float*)d_in[14];
    const float* s1  = (const float*)d_in[15];
    const float* b1  = (const float*)d_in[16];
    const float* W2  = (const float*)d_in[17];
    const float* s2  = (const float*)d_in[18];
    const float* b2  = (const float*)d_in[19];
    const float* W3  = (const float*)d_in[20];
    const float* s3  = (const float*)d_in[21];
    const float* b3  = (const float*)d_in[22];
    const float* W4  = (const float*)d_in[23];
    const float* s4  = (const float*)d_in[24];
    const float* b4  = (const float*)d_in[25];
    (void)in_sizes; (void)n_in; (void)out_size; (void)ws_size;

    char* wsp = (char*)d_ws;
    float* outp = (float*)d_out;

    hipMemsetAsync(wsp + WS_STRIPE, 0, 16 * 128 * sizeof(float), stream);
    kP0<<<NUNITS, 256, 0, stream>>>(feature, xyz, tW1, ts1, tb1, tW2, ts2, tb2,
                                    W2, s2, b2, wsp);
    kP23<<<NUNITS, 256, 0, stream>>>(nidx, xyz, tW3, ts3, tb3, tW4, tb4,
                                     W1, s1, b1, W3, s3, b3, W4, s4, b4, wsp, outp);
}

// Round 3
// 156.949 us; speedup vs baseline: 1.0631x; 1.0631x over previous
//
#include <hip/hip_runtime.h>

#define NPTS   65536
#define TOTAL  (2 * NPTS)
#define NUNITS 1024            // units of 128 points

typedef __attribute__((ext_vector_type(8)))  short short8;
typedef __attribute__((ext_vector_type(16))) float float16;
union F8 { uint4 u; short8 s; };

// ws byte offsets
#define WS_STRIPE 0                               // fp32[16][128], memset 0
#define WS_T1A    8192                            // bf16[TOTAL][32] f_nei, 64B rows
#define WS_T1B    (8192 + TOTAL * 64)             // (unused; kept for layout stability)
#define WS_T2     (8192 + TOTAL * 64 + TOTAL * 8) // bf16[TOTAL][32] feat, 64B rows
#define WS_H      (8192 + TOTAL * 64 + TOTAL * 8 + TOTAL * 64) // bf16[TOTAL][32] h, 64B rows

__device__ __forceinline__ unsigned short f2bf(float x) {
    unsigned u = __float_as_uint(x);
    return (unsigned short)((u + 0x7FFFu + ((u >> 16) & 1u)) >> 16);
}
__device__ __forceinline__ unsigned pk2(float a, float b) {
    return (unsigned)f2bf(a) | ((unsigned)f2bf(b) << 16);
}
__device__ __forceinline__ float relu(float x) { return x > 0.f ? x : 0.f; }
__device__ __forceinline__ uint4 pk8(const float* e) {
    uint4 u;
    u.x = pk2(e[0], e[1]); u.y = pk2(e[2], e[3]);
    u.z = pk2(e[4], e[5]); u.w = pk2(e[6], e[7]);
    return u;
}
__device__ __forceinline__ float16 zero16() {
    float16 z;
#pragma unroll
    for (int i = 0; i < 16; i++) z[i] = 0.f;
    return z;
}
// packed 2x16-bit max; valid as bf16 max because all values are relu outputs
// (bit patterns in [0, 0x7F7F], where i16 order == float order)
__device__ __forceinline__ unsigned pkmax(unsigned a, unsigned b) {
    unsigned d;
    asm("v_pk_max_i16 %0, %1, %2" : "=v"(d) : "v"(a), "v"(b));
    return d;
}

// ===== K0: tnet trunk + block max + striped atomics; f_nei GEMM + feat copy =====
__global__ __launch_bounds__(256) void kP0(
    const float* __restrict__ feature, const float* __restrict__ xyz,
    const float* __restrict__ tW1, const float* __restrict__ ts1, const float* __restrict__ tb1,
    const float* __restrict__ tW2, const float* __restrict__ ts2, const float* __restrict__ tb2,
    const float* __restrict__ W2,  const float* __restrict__ s2,  const float* __restrict__ b2,
    char* ws)
{
    __shared__ float red[4][64];
    float* stripe       = (float*)(ws + WS_STRIPE);
    unsigned short* t1a = (unsigned short*)(ws + WS_T1A);
    unsigned short* t2  = (unsigned short*)(ws + WS_T2);
    const int lane = threadIdx.x & 63, wv = threadIdx.x >> 6;
    const int col = lane & 31, h = lane >> 5;
    const float16 z = zero16();
    const int u = blockIdx.x;                   // 1024 blocks, 128 pts each
    const int b = u >> 9;
    float e[8];
    // trunk weights: tW1*ts1 (VALU side), tW2^T*ts2 (B-frags)
    float aw0[8], aw1[8], aw2[8], bb[8];
#pragma unroll
    for (int j = 0; j < 8; j++) {
        int k = 8 * h + j; float s = ts1[k];
        aw0[j] = tW1[k] * s; aw1[j] = tW1[16 + k] * s; aw2[j] = tW1[32 + k] * s;
        bb[j] = tb1[k];
    }
    F8 bf0, bf1;
#pragma unroll
    for (int j = 0; j < 8; j++) e[j] = tW2[(8 * h + j) * 64 + col] * ts2[col];
    bf0.u = pk8(e);
#pragma unroll
    for (int j = 0; j < 8; j++) e[j] = tW2[(8 * h + j) * 64 + 32 + col] * ts2[32 + col];
    bf1.u = pk8(e);
    // f_nei weights: W2^T folded as A-frags
    F8 a0, a1;
    float sc2 = s2[col];
#pragma unroll
    for (int j = 0; j < 8; j++) e[j] = W2[(8 * h + j) * 32 + col] * sc2;
    a0.u = pk8(e);
#pragma unroll
    for (int j = 0; j < 8; j++) e[j] = W2[(16 + 8 * h + j) * 32 + col] * sc2;
    a1.u = pk8(e);
    float b2v[16];
#pragma unroll
    for (int r = 0; r < 16; r++) b2v[r] = b2[(r & 3) + 8 * (r >> 2) + 4 * h];

    int base = u * 128 + wv * 32;
    // trunk + max
    const float* xp = xyz + (size_t)(base + col) * 3;
    float x0 = xp[0], x1 = xp[1], x2 = xp[2];
    float hv[8];
#pragma unroll
    for (int j = 0; j < 8; j++)
        hv[j] = relu(x0 * aw0[j] + x1 * aw1[j] + x2 * aw2[j] + bb[j]);
    F8 af; af.u = pk8(hv);
    float16 c0 = __builtin_amdgcn_mfma_f32_32x32x16_bf16(af.s, bf0.s, z, 0, 0, 0);
    float16 c1 = __builtin_amdgcn_mfma_f32_32x32x16_bf16(af.s, bf1.s, z, 0, 0, 0);
    float v0 = c0[0], v1 = c1[0];
#pragma unroll
    for (int i = 1; i < 16; i++) { v0 = fmaxf(v0, c0[i]); v1 = fmaxf(v1, c1[i]); }
    v0 = fmaxf(v0, __shfl_xor(v0, 32));
    v1 = fmaxf(v1, __shfl_xor(v1, 32));
    if (h == 0) { red[wv][col] = v0; red[wv][32 + col] = v1; }
    __syncthreads();
    if (threadIdx.x < 64) {
        int c = threadIdx.x;
        float m = fmaxf(fmaxf(red[0][c], red[1][c]), fmaxf(red[2][c], red[3][c]));
        float val = relu(m + tb2[c]);           // bias/relu after max: monotone, valid
        atomicMax((unsigned*)(stripe + (u & 15) * 128 + b * 64 + c), __float_as_uint(val));
    }
    // f_nei GEMM + raw feat copy
    int pt = base + col;
    const float* fb = feature + (size_t)b * 32 * NPTS + (pt & (NPTS - 1));
    float v[8];
    F8 f0, f1;
#pragma unroll
    for (int j = 0; j < 8; j++) v[j] = fb[(size_t)(8 * h + j) * NPTS];
    f0.u = pk8(v);
#pragma unroll
    for (int j = 0; j < 8; j++) v[j] = fb[(size_t)(16 + 8 * h + j) * NPTS];
    f1.u = pk8(v);
    *(uint4*)(t2 + (size_t)pt * 32 + 8 * h) = f0.u;
    *(uint4*)(t2 + (size_t)pt * 32 + 16 + 8 * h) = f1.u;
    float16 acc = z;
    acc = __builtin_amdgcn_mfma_f32_32x32x16_bf16(a0.s, f0.s, acc, 0, 0, 0);
    acc = __builtin_amdgcn_mfma_f32_32x32x16_bf16(a1.s, f1.s, acc, 0, 0, 0);
#pragma unroll
    for (int q = 0; q < 4; q++) {
        int r = 4 * q;
        uint2 uu;
        uu.x = pk2(relu(acc[r] + b2v[r]), relu(acc[r + 1] + b2v[r + 1]));
        uu.y = pk2(relu(acc[r + 2] + b2v[r + 2]), relu(acc[r + 3] + b2v[r + 3]));
        *(uint2*)(t1a + (size_t)pt * 32 + 8 * q + 4 * h) = uu;
    }
}

// ===== K1h: tnet head (T per block) + per-point h = relu(W3^T[f_nei;f_xyz]s3+b3)
//       h depends only on the point, so compute it ONCE here (dense, coalesced)
//       instead of per (point,neighbor) pair in the gather loop. =====
__global__ __launch_bounds__(256) void kP1h(
    const float* __restrict__ xyz,
    const float* __restrict__ tW3, const float* __restrict__ ts3, const float* __restrict__ tb3,
    const float* __restrict__ tW4, const float* __restrict__ tb4,
    const float* __restrict__ W1,  const float* __restrict__ s1,  const float* __restrict__ b1,
    const float* __restrict__ W3,  const float* __restrict__ s3,  const float* __restrict__ b3,
    char* ws)
{
    __shared__ unsigned short hst[128 * 40];
    const float* stripe = (const float*)(ws + WS_STRIPE);
    const unsigned short* t1a = (const unsigned short*)(ws + WS_T1A);
    unsigned short* hT = (unsigned short*)(ws + WS_H);
    const int lane = threadIdx.x & 63, wv = threadIdx.x >> 6;
    const int col = lane & 31, h = lane >> 5;
    const float16 z = zero16();
    const int u = blockIdx.x;
    const int batch = u >> 9;
    const int base = u * 128;

    // ---- tnet head prologue (identical op order to the original kP1) ----
    float hm = 0.f;
#pragma unroll
    for (int s = 0; s < 16; s++)
        hm = fmaxf(hm, stripe[s * 128 + batch * 64 + lane]);
    float vv[16];
    {
        const float4* trow = (const float4*)(tW3 + lane * 16);
#pragma unroll
        for (int q = 0; q < 4; q++) {
            float4 t4 = trow[q];
            vv[4 * q + 0] = hm * t4.x; vv[4 * q + 1] = hm * t4.y;
            vv[4 * q + 2] = hm * t4.z; vv[4 * q + 3] = hm * t4.w;
        }
    }
#pragma unroll
    for (int off = 1; off < 64; off <<= 1) {
#pragma unroll
        for (int c = 0; c < 16; c++) vv[c] += __shfl_xor(vv[c], off);
    }
    float T[9];
#pragma unroll
    for (int j = 0; j < 9; j++) T[j] = tb4[j];
#pragma unroll
    for (int c = 0; c < 16; c++) {
        float h3 = relu(vv[c] * ts3[c] + tb3[c]);
#pragma unroll
        for (int j = 0; j < 9; j++) T[j] += h3 * tW4[c * 9 + j];
    }
    T[0] += 1.f; T[4] += 1.f; T[8] += 1.f;
#pragma unroll
    for (int j = 0; j < 9; j++)
        T[j] = __uint_as_float(__builtin_amdgcn_readfirstlane(__float_as_uint(T[j])));

    float e[8];
    // W3^T folded B-frags (k>=35 zero)
    F8 w0, w1, w2, zf;
    zf.u.x = zf.u.y = zf.u.z = zf.u.w = 0u;
    float sc3 = s3[col];
#pragma unroll
    for (int j = 0; j < 8; j++) e[j] = W3[(8 * h + j) * 32 + col] * sc3;
    w0.u = pk8(e);
#pragma unroll
    for (int j = 0; j < 8; j++) e[j] = W3[(16 + 8 * h + j) * 32 + col] * sc3;
    w1.u = pk8(e);
    w2 = zf;
    if (h == 0) {
        float e2[8] = {0.f, 0.f, 0.f, 0.f, 0.f, 0.f, 0.f, 0.f};
#pragma unroll
        for (int j = 0; j < 3; j++) e2[j] = W3[(32 + j) * 32 + col] * sc3;
        w2.u = pk8(e2);
    }
    float b3v = b3[col];

    // own-point A-frags: f_nei row (coalesced) + f_xyz computed in place
    int pt = base + wv * 32 + col;
    const unsigned short* ap = t1a + (size_t)pt * 32;
    F8 ca0, ca1;
    ca0.u = *(const uint4*)(ap + 8 * h);
    ca1.u = *(const uint4*)(ap + 16 + 8 * h);
    const float* xp = xyz + (size_t)pt * 3;
    float x0 = xp[0], x1 = xp[1], x2 = xp[2];
    F8 ca2 = zf;
    {
        // exact same f32 op order + bf16 rounding as the original kP1/kP23
        float q0 = x0 * T[0] + x1 * T[3] + x2 * T[6];
        float q1 = x0 * T[1] + x1 * T[4] + x2 * T[7];
        float q2 = x0 * T[2] + x1 * T[5] + x2 * T[8];
        float r0 = relu((q0 * W1[0] + q1 * W1[3] + q2 * W1[6]) * s1[0] + b1[0]);
        float r1 = relu((q0 * W1[1] + q1 * W1[4] + q2 * W1[7]) * s1[1] + b1[1]);
        float r2 = relu((q0 * W1[2] + q1 * W1[5] + q2 * W1[8]) * s1[2] + b1[2]);
        if (h == 0) { ca2.u.x = pk2(r0, r1); ca2.u.y = pk2(r2, 0.f); }
        else        { ca2 = zf; }
    }
    float16 acc = z;
    acc = __builtin_amdgcn_mfma_f32_32x32x16_bf16(ca0.s, w0.s, acc, 0, 0, 0);
    acc = __builtin_amdgcn_mfma_f32_32x32x16_bf16(ca1.s, w1.s, acc, 0, 0, 0);
    acc = __builtin_amdgcn_mfma_f32_32x32x16_bf16(ca2.s, w2.s, acc, 0, 0, 0);
    // D: row = point slot (r&3)+8*(r>>2)+4h, col = output channel; transpose via LDS
#pragma unroll
    for (int r = 0; r < 16; r++) {
        int row = (r & 3) + 8 * (r >> 2) + 4 * h;
        hst[(wv * 32 + row) * 40 + col] = f2bf(relu(acc[r] + b3v));
    }
    // same-wave read back (rows wv*32..wv*32+31 written by this wave) + store
    int lr = lane >> 1, c2 = lane & 1;
    int grow = wv * 32 + lr;
    uint4 d0 = *(const uint4*)(hst + grow * 40 + 8 * c2);
    uint4 d1 = *(const uint4*)(hst + grow * 40 + 16 + 8 * c2);
    unsigned short* hrow = hT + (size_t)(base + grow) * 32;
    *(uint4*)(hrow + 8 * c2) = d0;
    *(uint4*)(hrow + 16 + 8 * c2) = d1;
}

// ===== K23: gather h rows + packed bf16 max over K + output GEMM =====
__global__ __launch_bounds__(256) void kP23(
    const int* __restrict__ nidx,
    const float* __restrict__ W4, const float* __restrict__ s4, const float* __restrict__ b4,
    char* ws, float* __restrict__ out)
{
    __shared__ unsigned short mld[128 * 40];
    const unsigned short* t2 = (const unsigned short*)(ws + WS_T2);
    const unsigned short* hT = (const unsigned short*)(ws + WS_H);
    const int tid = threadIdx.x;
    const int lane = tid & 63, wv = tid >> 6;
    const int col = lane & 31, h = lane >> 5;
    const float16 z = zero16();

    // XCD-batch affinity: blk&7 is XCD slot; slot>=4 -> batch 1
    int slot = blockIdx.x & 7, batch = slot >> 2;
    int grp = (blockIdx.x >> 3) * 4 + (slot & 3);   // [0, 512) within batch
    int u = batch * 512 + grp;
    int base = u * 128;

    // ---- gather-max: thread (p = tid>>1, c2 = tid&1) owns channels
    //      [8c2,8c2+8) and [16+8c2,24+8c2) of point p. Adjacent lanes read
    //      adjacent 16B chunks of the same 64B h row. ----
    {
        int p = tid >> 1, c2 = tid & 1;
        const int4* ip = (const int4*)(nidx + (size_t)(base + p) * 16);
        int4 I0 = ip[0], I1 = ip[1], I2 = ip[2], I3 = ip[3];
        int idx[16] = { I0.x, I0.y, I0.z, I0.w, I1.x, I1.y, I1.z, I1.w,
                        I2.x, I2.y, I2.z, I2.w, I3.x, I3.y, I3.z, I3.w };
        const unsigned short* hbase = hT + (((size_t)batch << 16) * 32);
        uint4 pfA[8], pfB[8];
#pragma unroll
        for (int k = 0; k < 8; k++) {
            const unsigned short* hp = hbase + (size_t)(unsigned)idx[k] * 32;
            pfA[k] = *(const uint4*)(hp + 8 * c2);        // ch [8c2, 8c2+8)
            pfB[k] = *(const uint4*)(hp + 16 + 8 * c2);   // ch [16+8c2, 24+8c2)
        }
        unsigned m0 = 0u, m1 = 0u, m2 = 0u, m3 = 0u,
                 m4 = 0u, m5 = 0u, m6 = 0u, m7 = 0u;     // relu => >= 0, 0-init safe
#pragma unroll
        for (int k = 0; k < 16; k++) {
            const int s = k & 7;
            uint4 A = pfA[s], B = pfB[s];
            if (k + 8 < 16) {
                const unsigned short* hp = hbase + (size_t)(unsigned)idx[k + 8] * 32;
                pfA[s] = *(const uint4*)(hp + 8 * c2);
                pfB[s] = *(const uint4*)(hp + 16 + 8 * c2);
            }
            m0 = pkmax(m0, A.x); m1 = pkmax(m1, A.y);
            m2 = pkmax(m2, A.z); m3 = pkmax(m3, A.w);
            m4 = pkmax(m4, B.x); m5 = pkmax(m5, B.y);
            m6 = pkmax(m6, B.z); m7 = pkmax(m7, B.w);
        }
        uint4 wa, wb;
        wa.x = m0; wa.y = m1; wa.z = m2; wa.w = m3;
        wb.x = m4; wb.y = m5; wb.z = m6; wb.w = m7;
        *(uint4*)(mld + p * 40 + 8 * c2) = wa;
        *(uint4*)(mld + p * 40 + 16 + 8 * c2) = wb;
    }

    // ---- epilogue weight prep AFTER the loop (keeps loop VGPR pressure low) ----
    float e[8];
    F8 aw[4];
    float sc4 = s4[col];
#pragma unroll
    for (int t = 0; t < 4; t++) {
#pragma unroll
        for (int j = 0; j < 8; j++) e[j] = W4[(16 * t + 8 * h + j) * 32 + col] * sc4;
        aw[t].u = pk8(e);
    }
    float b4v[16];
#pragma unroll
    for (int r = 0; r < 16; r++) b4v[r] = b4[(r & 3) + 8 * (r >> 2) + 4 * h];

    // output GEMM: 32 pts per wave; m read from LDS (same wave -> no barrier:
    // row wv*32+col was written by tids [64wv, 64wv+64) = this wave)
    int p_loc = wv * 32 + col;
    int p = base + p_loc;
    const unsigned short* bp = t2 + (size_t)p * 32 + 8 * h;
    F8 x0, x1, x2, x3;
    x0.u = *(const uint4*)(bp);
    x1.u = *(const uint4*)(bp + 16);
    const unsigned short* mp = mld + p_loc * 40;
    uint2 q0 = *(const uint2*)(mp + 8 * h);
    uint2 q1 = *(const uint2*)(mp + 8 * h + 4);
    uint2 q2 = *(const uint2*)(mp + 16 + 8 * h);
    uint2 q3 = *(const uint2*)(mp + 16 + 8 * h + 4);
    x2.u.x = q0.x; x2.u.y = q0.y; x2.u.z = q1.x; x2.u.w = q1.y;
    x3.u.x = q2.x; x3.u.y = q2.y; x3.u.z = q3.x; x3.u.w = q3.y;
    float16 acc = z;
    acc = __builtin_amdgcn_mfma_f32_32x32x16_bf16(aw[0].s, x0.s, acc, 0, 0, 0);
    acc = __builtin_amdgcn_mfma_f32_32x32x16_bf16(aw[1].s, x1.s, acc, 0, 0, 0);
    acc = __builtin_amdgcn_mfma_f32_32x32x16_bf16(aw[2].s, x2.s, acc, 0, 0, 0);
    acc = __builtin_amdgcn_mfma_f32_32x32x16_bf16(aw[3].s, x3.s, acc, 0, 0, 0);
    float* ob = out + (size_t)(batch * 32) * NPTS + (p & (NPTS - 1));
#pragma unroll
    for (int r = 0; r < 16; r++) {
        int o = (r & 3) + 8 * (r >> 2) + 4 * h;
        ob[(size_t)o * NPTS] = relu(acc[r] + b4v[r]);
    }
}

extern "C" void kernel_launch(void* const* d_in, const int* in_sizes, int n_in,
                              void* d_out, int out_size, void* d_ws, size_t ws_size,
                              hipStream_t stream)
{
    const float* feature = (const float*)d_in[0];
    const float* xyz     = (const float*)d_in[1];
    const int*   nidx    = (const int*)d_in[2];
    const float* tW1 = (const float*)d_in[3];
    const float* ts1 = (const float*)d_in[4];
    const float* tb1 = (const float*)d_in[5];
    const float* tW2 = (const float*)d_in[6];
    const float* ts2 = (const float*)d_in[7];
    const float* tb2 = (const float*)d_in[8];
    const float* tW3 = (const float*)d_in[9];
    const float* ts3 = (const float*)d_in[10];
    const float* tb3 = (const float*)d_in[11];
    const float* tW4 = (const float*)d_in[12];
    const float* tb4 = (const float*)d_in[13];
    const float* W1  = (const float*)d_in[14];
    const float* s1  = (const float*)d_in[15];
    const float* b1  = (const float*)d_in[16];
    const float* W2  = (const float*)d_in[17];
    const float* s2  = (const float*)d_in[18];
    const float* b2  = (const float*)d_in[19];
    const float* W3  = (const float*)d_in[20];
    const float* s3  = (const float*)d_in[21];
    const float* b3  = (const float*)d_in[22];
    const float* W4  = (const float*)d_in[23];
    const float* s4  = (const float*)d_in[24];
    const float* b4  = (const float*)d_in[25];
    (void)in_sizes; (void)n_in; (void)out_size; (void)ws_size;

    char* wsp = (char*)d_ws;
    float* outp = (float*)d_out;

    hipMemsetAsync(wsp + WS_STRIPE, 0, 16 * 128 * sizeof(float), stream);
    kP0<<<NUNITS, 256, 0, stream>>>(feature, xyz, tW1, ts1, tb1, tW2, ts2, tb2,
                                    W2, s2, b2, wsp);
    kP1h<<<NUNITS, 256, 0, stream>>>(xyz, tW3, ts3, tb3, tW4, tb4,
                                     W1, s1, b1, W3, s3, b3, wsp);
    kP23<<<NUNITS, 256, 0, stream>>>(nidx, W4, s4, b4, wsp, outp);
}

// Round 5
// 156.563 us; speedup vs baseline: 1.0657x; 1.0025x over previous
//
#include <hip/hip_runtime.h>

#define NPTS   65536
#define TOTAL  (2 * NPTS)
#define NUNITS 1024            // units of 128 points

typedef __attribute__((ext_vector_type(8)))  short short8;
typedef __attribute__((ext_vector_type(16))) float float16;
union F8 { uint4 u; short8 s; };

// ws byte offsets
#define WS_STRIPE 0                               // fp32[16][128], memset 0
#define WS_T1A    8192                            // bf16[TOTAL][32] f_nei, 64B rows
#define WS_T1B    (8192 + TOTAL * 64)             // (unused; kept for layout stability)
#define WS_T2     (8192 + TOTAL * 64 + TOTAL * 8) // bf16[TOTAL][32] feat, 64B rows
#define WS_H      (8192 + TOTAL * 64 + TOTAL * 8 + TOTAL * 64) // bf16[TOTAL][32] h, 64B rows

__device__ __forceinline__ unsigned short f2bf(float x) {
    unsigned u = __float_as_uint(x);
    return (unsigned short)((u + 0x7FFFu + ((u >> 16) & 1u)) >> 16);
}
__device__ __forceinline__ unsigned pk2(float a, float b) {
    return (unsigned)f2bf(a) | ((unsigned)f2bf(b) << 16);
}
__device__ __forceinline__ float relu(float x) { return x > 0.f ? x : 0.f; }
__device__ __forceinline__ uint4 pk8(const float* e) {
    uint4 u;
    u.x = pk2(e[0], e[1]); u.y = pk2(e[2], e[3]);
    u.z = pk2(e[4], e[5]); u.w = pk2(e[6], e[7]);
    return u;
}
__device__ __forceinline__ float16 zero16() {
    float16 z;
#pragma unroll
    for (int i = 0; i < 16; i++) z[i] = 0.f;
    return z;
}
// packed 2x16-bit max; valid as bf16 max because all values are relu outputs
// (bit patterns in [0, 0x7F7F], where i16 order == float order)
__device__ __forceinline__ unsigned pkmax(unsigned a, unsigned b) {
    unsigned d;
    asm("v_pk_max_i16 %0, %1, %2" : "=v"(d) : "v"(a), "v"(b));
    return d;
}

// ===== K0: tnet trunk + block max + striped atomics; f_nei GEMM + feat copy =====
__global__ __launch_bounds__(256) void kP0(
    const float* __restrict__ feature, const float* __restrict__ xyz,
    const float* __restrict__ tW1, const float* __restrict__ ts1, const float* __restrict__ tb1,
    const float* __restrict__ tW2, const float* __restrict__ ts2, const float* __restrict__ tb2,
    const float* __restrict__ W2,  const float* __restrict__ s2,  const float* __restrict__ b2,
    char* ws)
{
    __shared__ float red[4][64];
    float* stripe       = (float*)(ws + WS_STRIPE);
    unsigned short* t1a = (unsigned short*)(ws + WS_T1A);
    unsigned short* t2  = (unsigned short*)(ws + WS_T2);
    const int lane = threadIdx.x & 63, wv = threadIdx.x >> 6;
    const int col = lane & 31, h = lane >> 5;
    const float16 z = zero16();
    const int u = blockIdx.x;                   // 1024 blocks, 128 pts each
    const int b = u >> 9;
    float e[8];
    // trunk weights: tW1*ts1 (VALU side), tW2^T*ts2 (B-frags)
    float aw0[8], aw1[8], aw2[8], bb[8];
#pragma unroll
    for (int j = 0; j < 8; j++) {
        int k = 8 * h + j; float s = ts1[k];
        aw0[j] = tW1[k] * s; aw1[j] = tW1[16 + k] * s; aw2[j] = tW1[32 + k] * s;
        bb[j] = tb1[k];
    }
    F8 bf0, bf1;
#pragma unroll
    for (int j = 0; j < 8; j++) e[j] = tW2[(8 * h + j) * 64 + col] * ts2[col];
    bf0.u = pk8(e);
#pragma unroll
    for (int j = 0; j < 8; j++) e[j] = tW2[(8 * h + j) * 64 + 32 + col] * ts2[32 + col];
    bf1.u = pk8(e);
    // f_nei weights: W2^T folded as A-frags
    F8 a0, a1;
    float sc2 = s2[col];
#pragma unroll
    for (int j = 0; j < 8; j++) e[j] = W2[(8 * h + j) * 32 + col] * sc2;
    a0.u = pk8(e);
#pragma unroll
    for (int j = 0; j < 8; j++) e[j] = W2[(16 + 8 * h + j) * 32 + col] * sc2;
    a1.u = pk8(e);
    float b2v[16];
#pragma unroll
    for (int r = 0; r < 16; r++) b2v[r] = b2[(r & 3) + 8 * (r >> 2) + 4 * h];

    int base = u * 128 + wv * 32;
    // trunk + max
    const float* xp = xyz + (size_t)(base + col) * 3;
    float x0 = xp[0], x1 = xp[1], x2 = xp[2];
    float hv[8];
#pragma unroll
    for (int j = 0; j < 8; j++)
        hv[j] = relu(x0 * aw0[j] + x1 * aw1[j] + x2 * aw2[j] + bb[j]);
    F8 af; af.u = pk8(hv);
    float16 c0 = __builtin_amdgcn_mfma_f32_32x32x16_bf16(af.s, bf0.s, z, 0, 0, 0);
    float16 c1 = __builtin_amdgcn_mfma_f32_32x32x16_bf16(af.s, bf1.s, z, 0, 0, 0);
    float v0 = c0[0], v1 = c1[0];
#pragma unroll
    for (int i = 1; i < 16; i++) { v0 = fmaxf(v0, c0[i]); v1 = fmaxf(v1, c1[i]); }
    v0 = fmaxf(v0, __shfl_xor(v0, 32));
    v1 = fmaxf(v1, __shfl_xor(v1, 32));
    if (h == 0) { red[wv][col] = v0; red[wv][32 + col] = v1; }
    __syncthreads();
    if (threadIdx.x < 64) {
        int c = threadIdx.x;
        float m = fmaxf(fmaxf(red[0][c], red[1][c]), fmaxf(red[2][c], red[3][c]));
        float val = relu(m + tb2[c]);           // bias/relu after max: monotone, valid
        atomicMax((unsigned*)(stripe + (u & 15) * 128 + b * 64 + c), __float_as_uint(val));
    }
    // f_nei GEMM + raw feat copy
    int pt = base + col;
    const float* fb = feature + (size_t)b * 32 * NPTS + (pt & (NPTS - 1));
    float v[8];
    F8 f0, f1;
#pragma unroll
    for (int j = 0; j < 8; j++) v[j] = fb[(size_t)(8 * h + j) * NPTS];
    f0.u = pk8(v);
#pragma unroll
    for (int j = 0; j < 8; j++) v[j] = fb[(size_t)(16 + 8 * h + j) * NPTS];
    f1.u = pk8(v);
    *(uint4*)(t2 + (size_t)pt * 32 + 8 * h) = f0.u;
    *(uint4*)(t2 + (size_t)pt * 32 + 16 + 8 * h) = f1.u;
    float16 acc = z;
    acc = __builtin_amdgcn_mfma_f32_32x32x16_bf16(a0.s, f0.s, acc, 0, 0, 0);
    acc = __builtin_amdgcn_mfma_f32_32x32x16_bf16(a1.s, f1.s, acc, 0, 0, 0);
#pragma unroll
    for (int q = 0; q < 4; q++) {
        int r = 4 * q;
        uint2 uu;
        uu.x = pk2(relu(acc[r] + b2v[r]), relu(acc[r + 1] + b2v[r + 1]));
        uu.y = pk2(relu(acc[r + 2] + b2v[r + 2]), relu(acc[r + 3] + b2v[r + 3]));
        *(uint2*)(t1a + (size_t)pt * 32 + 8 * q + 4 * h) = uu;
    }
}

// ===== K1h: tnet head (T per block) + per-point h = relu(W3^T[f_nei;f_xyz]s3+b3)
//       h depends only on the point, so compute it ONCE here (dense, coalesced)
//       instead of per (point,neighbor) pair in the gather loop. =====
__global__ __launch_bounds__(256) void kP1h(
    const float* __restrict__ xyz,
    const float* __restrict__ tW3, const float* __restrict__ ts3, const float* __restrict__ tb3,
    const float* __restrict__ tW4, const float* __restrict__ tb4,
    const float* __restrict__ W1,  const float* __restrict__ s1,  const float* __restrict__ b1,
    const float* __restrict__ W3,  const float* __restrict__ s3,  const float* __restrict__ b3,
    char* ws)
{
    __shared__ unsigned short hst[128 * 40];
    const float* stripe = (const float*)(ws + WS_STRIPE);
    const unsigned short* t1a = (const unsigned short*)(ws + WS_T1A);
    unsigned short* hT = (unsigned short*)(ws + WS_H);
    const int lane = threadIdx.x & 63, wv = threadIdx.x >> 6;
    const int col = lane & 31, h = lane >> 5;
    const float16 z = zero16();
    const int u = blockIdx.x;
    const int batch = u >> 9;
    const int base = u * 128;

    // ---- tnet head prologue (identical op order to the original kP1) ----
    float hm = 0.f;
#pragma unroll
    for (int s = 0; s < 16; s++)
        hm = fmaxf(hm, stripe[s * 128 + batch * 64 + lane]);
    float vv[16];
    {
        const float4* trow = (const float4*)(tW3 + lane * 16);
#pragma unroll
        for (int q = 0; q < 4; q++) {
            float4 t4 = trow[q];
            vv[4 * q + 0] = hm * t4.x; vv[4 * q + 1] = hm * t4.y;
            vv[4 * q + 2] = hm * t4.z; vv[4 * q + 3] = hm * t4.w;
        }
    }
#pragma unroll
    for (int off = 1; off < 64; off <<= 1) {
#pragma unroll
        for (int c = 0; c < 16; c++) vv[c] += __shfl_xor(vv[c], off);
    }
    float T[9];
#pragma unroll
    for (int j = 0; j < 9; j++) T[j] = tb4[j];
#pragma unroll
    for (int c = 0; c < 16; c++) {
        float h3 = relu(vv[c] * ts3[c] + tb3[c]);
#pragma unroll
        for (int j = 0; j < 9; j++) T[j] += h3 * tW4[c * 9 + j];
    }
    T[0] += 1.f; T[4] += 1.f; T[8] += 1.f;
#pragma unroll
    for (int j = 0; j < 9; j++)
        T[j] = __uint_as_float(__builtin_amdgcn_readfirstlane(__float_as_uint(T[j])));

    float e[8];
    // W3^T folded B-frags (k>=35 zero)
    F8 w0, w1, w2, zf;
    zf.u.x = zf.u.y = zf.u.z = zf.u.w = 0u;
    float sc3 = s3[col];
#pragma unroll
    for (int j = 0; j < 8; j++) e[j] = W3[(8 * h + j) * 32 + col] * sc3;
    w0.u = pk8(e);
#pragma unroll
    for (int j = 0; j < 8; j++) e[j] = W3[(16 + 8 * h + j) * 32 + col] * sc3;
    w1.u = pk8(e);
    w2 = zf;
    if (h == 0) {
        float e2[8] = {0.f, 0.f, 0.f, 0.f, 0.f, 0.f, 0.f, 0.f};
#pragma unroll
        for (int j = 0; j < 3; j++) e2[j] = W3[(32 + j) * 32 + col] * sc3;
        w2.u = pk8(e2);
    }
    float b3v = b3[col];

    // own-point A-frags: f_nei row (coalesced) + f_xyz computed in place
    int pt = base + wv * 32 + col;
    const unsigned short* ap = t1a + (size_t)pt * 32;
    F8 ca0, ca1;
    ca0.u = *(const uint4*)(ap + 8 * h);
    ca1.u = *(const uint4*)(ap + 16 + 8 * h);
    const float* xp = xyz + (size_t)pt * 3;
    float x0 = xp[0], x1 = xp[1], x2 = xp[2];
    F8 ca2 = zf;
    {
        // exact same f32 op order + bf16 rounding as the original kP1/kP23
        float q0 = x0 * T[0] + x1 * T[3] + x2 * T[6];
        float q1 = x0 * T[1] + x1 * T[4] + x2 * T[7];
        float q2 = x0 * T[2] + x1 * T[5] + x2 * T[8];
        float r0 = relu((q0 * W1[0] + q1 * W1[3] + q2 * W1[6]) * s1[0] + b1[0]);
        float r1 = relu((q0 * W1[1] + q1 * W1[4] + q2 * W1[7]) * s1[1] + b1[1]);
        float r2 = relu((q0 * W1[2] + q1 * W1[5] + q2 * W1[8]) * s1[2] + b1[2]);
        if (h == 0) { ca2.u.x = pk2(r0, r1); ca2.u.y = pk2(r2, 0.f); }
        else        { ca2 = zf; }
    }
    float16 acc = z;
    acc = __builtin_amdgcn_mfma_f32_32x32x16_bf16(ca0.s, w0.s, acc, 0, 0, 0);
    acc = __builtin_amdgcn_mfma_f32_32x32x16_bf16(ca1.s, w1.s, acc, 0, 0, 0);
    acc = __builtin_amdgcn_mfma_f32_32x32x16_bf16(ca2.s, w2.s, acc, 0, 0, 0);
    // D: row = point slot (r&3)+8*(r>>2)+4h, col = output channel; transpose via LDS
#pragma unroll
    for (int r = 0; r < 16; r++) {
        int row = (r & 3) + 8 * (r >> 2) + 4 * h;
        hst[(wv * 32 + row) * 40 + col] = f2bf(relu(acc[r] + b3v));
    }
    // same-wave read back (rows wv*32..wv*32+31 written by this wave) + store
    int lr = lane >> 1, c2 = lane & 1;
    int grow = wv * 32 + lr;
    uint4 d0 = *(const uint4*)(hst + grow * 40 + 8 * c2);
    uint4 d1 = *(const uint4*)(hst + grow * 40 + 16 + 8 * c2);
    unsigned short* hrow = hT + (size_t)(base + grow) * 32;
    *(uint4*)(hrow + 8 * c2) = d0;
    *(uint4*)(hrow + 16 + 8 * c2) = d1;
}

// ===== K23: gather h rows + packed bf16 max over K + output GEMM =====
__global__ __launch_bounds__(256) void kP23(
    const int* __restrict__ nidx,
    const float* __restrict__ W4, const float* __restrict__ s4, const float* __restrict__ b4,
    char* ws, float* __restrict__ out)
{
    __shared__ unsigned short mld[128 * 40];
    const unsigned short* t2 = (const unsigned short*)(ws + WS_T2);
    const unsigned short* hT = (const unsigned short*)(ws + WS_H);
    const int tid = threadIdx.x;
    const int lane = tid & 63, wv = tid >> 6;
    const int col = lane & 31, h = lane >> 5;
    const float16 z = zero16();

    // XCD-batch affinity: blk&7 is XCD slot; slot>=4 -> batch 1
    int slot = blockIdx.x & 7, batch = slot >> 2;
    int grp = (blockIdx.x >> 3) * 4 + (slot & 3);   // [0, 512) within batch
    int u = batch * 512 + grp;
    int base = u * 128;

    // ---- gather-max: thread (p = tid>>1, c2 = tid&1) owns channels
    //      [8c2,8c2+8) and [16+8c2,24+8c2) of point p. Adjacent lanes read
    //      adjacent 16B chunks of the same 64B h row. ----
    {
        int p = tid >> 1, c2 = tid & 1;
        const int4* ip = (const int4*)(nidx + (size_t)(base + p) * 16);
        int4 I0 = ip[0], I1 = ip[1], I2 = ip[2], I3 = ip[3];
        int idx[16] = { I0.x, I0.y, I0.z, I0.w, I1.x, I1.y, I1.z, I1.w,
                        I2.x, I2.y, I2.z, I2.w, I3.x, I3.y, I3.z, I3.w };
        const unsigned short* hbase = hT + (((size_t)batch << 16) * 32);
        uint4 pfA[8], pfB[8];
#pragma unroll
        for (int k = 0; k < 8; k++) {
            const unsigned short* hp = hbase + (size_t)(unsigned)idx[k] * 32;
            pfA[k] = *(const uint4*)(hp + 8 * c2);        // ch [8c2, 8c2+8)
            pfB[k] = *(const uint4*)(hp + 16 + 8 * c2);   // ch [16+8c2, 24+8c2)
        }
        unsigned m0 = 0u, m1 = 0u, m2 = 0u, m3 = 0u,
                 m4 = 0u, m5 = 0u, m6 = 0u, m7 = 0u;     // relu => >= 0, 0-init safe
#pragma unroll
        for (int k = 0; k < 16; k++) {
            const int s = k & 7;
            uint4 A = pfA[s], B = pfB[s];
            if (k + 8 < 16) {
                const unsigned short* hp = hbase + (size_t)(unsigned)idx[k + 8] * 32;
                pfA[s] = *(const uint4*)(hp + 8 * c2);
                pfB[s] = *(const uint4*)(hp + 16 + 8 * c2);
            }
            m0 = pkmax(m0, A.x); m1 = pkmax(m1, A.y);
            m2 = pkmax(m2, A.z); m3 = pkmax(m3, A.w);
            m4 = pkmax(m4, B.x); m5 = pkmax(m5, B.y);
            m6 = pkmax(m6, B.z); m7 = pkmax(m7, B.w);
        }
        uint4 wa, wb;
        wa.x = m0; wa.y = m1; wa.z = m2; wa.w = m3;
        wb.x = m4; wb.y = m5; wb.z = m6; wb.w = m7;
        *(uint4*)(mld + p * 40 + 8 * c2) = wa;
        *(uint4*)(mld + p * 40 + 16 + 8 * c2) = wb;
    }

    // ---- epilogue weight prep AFTER the loop (keeps loop VGPR pressure low) ----
    float e[8];
    F8 aw[4];
    float sc4 = s4[col];
#pragma unroll
    for (int t = 0; t < 4; t++) {
#pragma unroll
        for (int j = 0; j < 8; j++) e[j] = W4[(16 * t + 8 * h + j) * 32 + col] * sc4;
        aw[t].u = pk8(e);
    }
    float b4v[16];
#pragma unroll
    for (int r = 0; r < 16; r++) b4v[r] = b4[(r & 3) + 8 * (r >> 2) + 4 * h];

    // output GEMM: 32 pts per wave; m read from LDS (same wave -> no barrier:
    // row wv*32+col was written by tids [64wv, 64wv+64) = this wave)
    int p_loc = wv * 32 + col;
    int p = base + p_loc;
    const unsigned short* bp = t2 + (size_t)p * 32 + 8 * h;
    F8 x0, x1, x2, x3;
    x0.u = *(const uint4*)(bp);
    x1.u = *(const uint4*)(bp + 16);
    const unsigned short* mp = mld + p_loc * 40;
    uint2 q0 = *(const uint2*)(mp + 8 * h);
    uint2 q1 = *(const uint2*)(mp + 8 * h + 4);
    uint2 q2 = *(const uint2*)(mp + 16 + 8 * h);
    uint2 q3 = *(const uint2*)(mp + 16 + 8 * h + 4);
    x2.u.x = q0.x; x2.u.y = q0.y; x2.u.z = q1.x; x2.u.w = q1.y;
    x3.u.x = q2.x; x3.u.y = q2.y; x3.u.z = q3.x; x3.u.w = q3.y;
    float16 acc = z;
    acc = __builtin_amdgcn_mfma_f32_32x32x16_bf16(aw[0].s, x0.s, acc, 0, 0, 0);
    acc = __builtin_amdgcn_mfma_f32_32x32x16_bf16(aw[1].s, x1.s, acc, 0, 0, 0);
    acc = __builtin_amdgcn_mfma_f32_32x32x16_bf16(aw[2].s, x2.s, acc, 0, 0, 0);
    acc = __builtin_amdgcn_mfma_f32_32x32x16_bf16(aw[3].s, x3.s, acc, 0, 0, 0);
    float* ob = out + (size_t)(batch * 32) * NPTS + (p & (NPTS - 1));
#pragma unroll
    for (int r = 0; r < 16; r++) {
        int o = (r & 3) + 8 * (r >> 2) + 4 * h;
        ob[(size_t)o * NPTS] = relu(acc[r] + b4v[r]);
    }
}

extern "C" void kernel_launch(void* const* d_in, const int* in_sizes, int n_in,
                              void* d_out, int out_size, void* d_ws, size_t ws_size,
                              hipStream_t stream)
{
    const float* feature = (const float*)d_in[0];
    const float* xyz     = (const float*)d_in[1];
    const int*   nidx    = (const int*)d_in[2];
    const float* tW1 = (const float*)d_in[3];
    const float* ts1 = (const float*)d_in[4];
    const float* tb1 = (const float*)d_in[5];
    const float* tW2 = (const float*)d_in[6];
    const float* ts2 = (const float*)d_in[7];
    const float* tb2 = (const float*)d_in[8];
    const float* tW3 = (const float*)d_in[9];
    const float* ts3 = (const float*)d_in[10];
    const float* tb3 = (const float*)d_in[11];
    const float* tW4 = (const float*)d_in[12];
    const float* tb4 = (const float*)d_in[13];
    const float* W1  = (const float*)d_in[14];
    const float* s1  = (const float*)d_in[15];
    const float* b1  = (const float*)d_in[16];
    const float* W2  = (const float*)d_in[17];
    const float* s2  = (const float*)d_in[18];
    const float* b2  = (const float*)d_in[19];
    const float* W3  = (const float*)d_in[20];
    const float* s3  = (const float*)d_in[21];
    const float* b3  = (const float*)d_in[22];
    const float* W4  = (const float*)d_in[23];
    const float* s4  = (const float*)d_in[24];
    const float* b4  = (const float*)d_in[25];
    (void)in_sizes; (void)n_in; (void)out_size; (void)ws_size;

    char* wsp = (char*)d_ws;
    float* outp = (float*)d_out;

    hipMemsetAsync(wsp + WS_STRIPE, 0, 16 * 128 * sizeof(float), stream);
    kP0<<<NUNITS, 256, 0, stream>>>(feature, xyz, tW1, ts1, tb1, tW2, ts2, tb2,
                                    W2, s2, b2, wsp);
    kP1h<<<NUNITS, 256, 0, stream>>>(xyz, tW3, ts3, tb3, tW4, tb4,
                                     W1, s1, b1, W3, s3, b3, wsp);
    kP23<<<NUNITS, 256, 0, stream>>>(nidx, W4, s4, b4, wsp, outp);
}